// Round 2
// baseline (1770.643 us; speedup 1.0000x reference)
//
#include <hip/hip_runtime.h>
#include <math.h>

namespace {

constexpr int Bz = 256;
constexpr int Sq = 43;
constexpr int Dm = 18;
constexpr int NHeads = 3;
constexpr int Dff = 2048;
constexpr int Am = 128;
constexpr int Nb = 7;
constexpr float EPSf = 1e-6f;

// ---------------------------------------------------------------------------
// LN1 + QKV projection for one row (y[18] in registers), writes q/k/v rows.
// Weight reads use uniform indices -> scalar loads.
// ---------------------------------------------------------------------------
__device__ __forceinline__ void ln_qkv_write(
    int row, const float* y, int ly,
    const float* __restrict__ Wq, const float* __restrict__ bq,
    const float* __restrict__ Wk, const float* __restrict__ bk,
    const float* __restrict__ Wv, const float* __restrict__ bv,
    const float* __restrict__ ln1a, const float* __restrict__ ln1b,
    float* __restrict__ qb, float* __restrict__ kb, float* __restrict__ vb)
{
    float mu = 0.f;
    #pragma unroll
    for (int d = 0; d < Dm; d++) mu += y[d];
    mu *= (1.f / Dm);
    float var = 0.f;
    #pragma unroll
    for (int d = 0; d < Dm; d++) { float t = y[d] - mu; var += t * t; }
    var *= (1.f / (Dm - 1));                 // ddof=1 (sample std)
    float isd = 1.f / (sqrtf(var) + EPSf);   // eps added to sd, not var
    float x2[Dm];
    #pragma unroll
    for (int d = 0; d < Dm; d++)
        x2[d] = ln1a[ly * Dm + d] * (y[d] - mu) * isd + ln1b[ly * Dm + d];
    const float* wq = Wq + ly * Dm * Dm;
    const float* wk = Wk + ly * Dm * Dm;
    const float* wv = Wv + ly * Dm * Dm;
    #pragma unroll 3
    for (int d = 0; d < Dm; d++) {
        float aq = bq[ly * Dm + d];
        float ak = bk[ly * Dm + d];
        float av = bv[ly * Dm + d];
        #pragma unroll
        for (int dd = 0; dd < Dm; dd++) {
            aq += x2[dd] * wq[dd * Dm + d];
            ak += x2[dd] * wk[dd * Dm + d];
            av += x2[dd] * wv[dd * Dm + d];
        }
        qb[row * Dm + d] = aq;
        kb[row * Dm + d] = ak;
        vb[row * Dm + d] = av;
    }
}

// ---------------------------------------------------------------------------
// k_init: x = src (copy), then LN1+QKV for layer 0. One thread per row.
// ---------------------------------------------------------------------------
__global__ __launch_bounds__(256) void k_init(
    const float* __restrict__ src, float* __restrict__ xg,
    const float* __restrict__ Wq, const float* __restrict__ bq,
    const float* __restrict__ Wk, const float* __restrict__ bk,
    const float* __restrict__ Wv, const float* __restrict__ bv,
    const float* __restrict__ ln1a, const float* __restrict__ ln1b,
    float* __restrict__ qb, float* __restrict__ kb, float* __restrict__ vb)
{
    int row = blockIdx.x * 256 + threadIdx.x;   // 43 blocks * 256 = 11008 exactly
    float y[Dm];
    #pragma unroll
    for (int d = 0; d < Dm; d++) {
        y[d] = src[row * Dm + d];
        xg[row * Dm + d] = y[d];
    }
    ln_qkv_write(row, y, 0, Wq, bq, Wk, bk, Wv, bv, ln1a, ln1b, qb, kb, vb);
}

// ---------------------------------------------------------------------------
// k_attn: one block per batch b, 64 threads, lane = query position i (<43).
// Streaming 2-pass softmax; K/V rows + Wo via uniform (scalar) loads.
// Fused: attention + output proj + residual + LN2 (writes x and x2).
// ---------------------------------------------------------------------------
__global__ __launch_bounds__(64) void k_attn(
    int layer,
    const float* __restrict__ qb, const float* __restrict__ kb,
    const float* __restrict__ vb,
    float* __restrict__ xg, float* __restrict__ x2g,
    const int* __restrict__ maskg,
    const float* __restrict__ Wo, const float* __restrict__ bo,
    const float* __restrict__ ln2a, const float* __restrict__ ln2b)
{
    int b = blockIdx.x;
    int i = threadIdx.x;
    bool act = (i < Sq);
    int row = b * Sq + (act ? i : (Sq - 1));   // clamp keeps reads in-bounds

    float q[Dm];
    #pragma unroll
    for (int d = 0; d < Dm; d++) q[d] = qb[row * Dm + d];

    float o[Dm];
    #pragma unroll
    for (int d = 0; d < Dm; d++) o[d] = 0.f;

    const float scale = 0.40824829046386296f;  // 1/sqrt(6)

    #pragma unroll
    for (int h = 0; h < NHeads; h++) {
        // pass 1: max
        float mx = -1e30f;
        for (int j = 0; j < Sq; j++) {
            const float* kr = kb + (b * Sq + j) * Dm + h * 6;
            float t = 0.f;
            #pragma unroll
            for (int d6 = 0; d6 < 6; d6++) t += q[h * 6 + d6] * kr[d6];
            t *= scale;
            if (maskg[b * Sq + j] == 0) t = -1e9f;
            mx = fmaxf(mx, t);
        }
        // pass 2: exp-sum + unnormalized PV
        float sum = 0.f;
        float o6[6];
        #pragma unroll
        for (int d6 = 0; d6 < 6; d6++) o6[d6] = 0.f;
        for (int j = 0; j < Sq; j++) {
            const float* kr = kb + (b * Sq + j) * Dm + h * 6;
            const float* vr = vb + (b * Sq + j) * Dm + h * 6;
            float t = 0.f;
            #pragma unroll
            for (int d6 = 0; d6 < 6; d6++) t += q[h * 6 + d6] * kr[d6];
            t *= scale;
            if (maskg[b * Sq + j] == 0) t = -1e9f;
            float e = __expf(t - mx);
            sum += e;
            #pragma unroll
            for (int d6 = 0; d6 < 6; d6++) o6[d6] += e * vr[d6];
        }
        float inv = 1.f / sum;
        #pragma unroll
        for (int d6 = 0; d6 < 6; d6++) o[h * 6 + d6] = o6[d6] * inv;
    }

    // output projection + residual
    const float* wo = Wo + layer * Dm * Dm;
    float y[Dm];
    #pragma unroll 3
    for (int d = 0; d < Dm; d++) {
        float t = bo[layer * Dm + d];
        #pragma unroll
        for (int dd = 0; dd < Dm; dd++) t += o[dd] * wo[dd * Dm + d];
        y[d] = xg[row * Dm + d] + t;
    }

    if (act) {
        #pragma unroll
        for (int d = 0; d < Dm; d++) xg[row * Dm + d] = y[d];
        // LN2 -> x2g
        float mu = 0.f;
        #pragma unroll
        for (int d = 0; d < Dm; d++) mu += y[d];
        mu *= (1.f / Dm);
        float var = 0.f;
        #pragma unroll
        for (int d = 0; d < Dm; d++) { float t = y[d] - mu; var += t * t; }
        var *= (1.f / (Dm - 1));
        float isd = 1.f / (sqrtf(var) + EPSf);
        #pragma unroll
        for (int d = 0; d < Dm; d++)
            x2g[row * Dm + d] =
                ln2a[layer * Dm + d] * (y[d] - mu) * isd + ln2b[layer * Dm + d];
    }
}

// ---------------------------------------------------------------------------
// k_ffn: 64 rows per block (172 blocks), 256 threads (4 waves).
// Phase 1: thread j computes h[j][r] for 64 rows (x2 rows via scalar loads,
//          W1 column in VGPRs), writes XOR-swizzled LDS.
// Phase 2: lane = row, wave = K-slice; W2 rows via scalar loads (SGPR fmac),
//          18 fp32 accumulators per lane. Cross-wave reduce at the end.
// Epilogue (wave 0): residual + write x, then LN1+QKV for layer+1 (fused).
// ---------------------------------------------------------------------------
__global__ __launch_bounds__(256) void k_ffn(
    int layer,
    const float* __restrict__ x2g, float* __restrict__ xg,
    const float* __restrict__ W1g, const float* __restrict__ b1g,
    const float* __restrict__ W2g, const float* __restrict__ b2g,
    int do_tail,
    const float* __restrict__ Wq, const float* __restrict__ bq,
    const float* __restrict__ Wk, const float* __restrict__ bk,
    const float* __restrict__ Wv, const float* __restrict__ bv,
    const float* __restrict__ ln1a, const float* __restrict__ ln1b,
    float* __restrict__ qb, float* __restrict__ kb, float* __restrict__ vb)
{
    __shared__ float Hc[64 * 256];   // exactly 64 KiB, XOR-swizzled

    const int tid  = threadIdx.x;
    const int lane = tid & 63;
    const int wv   = __builtin_amdgcn_readfirstlane(tid) >> 6;  // wave id (uniform)
    const int row0 = blockIdx.x * 64;

    const float* W1l = W1g + (size_t)layer * Dm * Dff;
    const float* W2l = W2g + (size_t)layer * Dff * Dm;
    const float* b1l = b1g + layer * Dff;
    const float* b2l = b2g + layer * Dm;

    float acc[Dm];
    #pragma unroll
    for (int d = 0; d < Dm; d++) acc[d] = 0.f;

    for (int c = 0; c < 8; c++) {
        const int j = c * 256 + tid;
        float w1[Dm];
        #pragma unroll
        for (int d = 0; d < Dm; d++) w1[d] = W1l[d * Dff + j];
        const float b1j = b1l[j];

        __syncthreads();   // protect Hc against previous chunk's readers
        // ---- phase 1: hidden activations for 64 rows ----
        #pragma unroll 4
        for (int r = 0; r < 64; r++) {
            const float* xr = x2g + (size_t)(row0 + r) * Dm;  // uniform -> s_load
            float h = b1j;
            #pragma unroll
            for (int d = 0; d < Dm; d++) h += xr[d] * w1[d];
            h = fmaxf(h, 0.f);
            Hc[r * 256 + (tid ^ (r & 31))] = h;
        }
        __syncthreads();
        // ---- phase 2: out += H-chunk @ W2-chunk, wave-split over K ----
        const float* w2base = W2l + (size_t)(c * 256) * Dm;
        #pragma unroll 4
        for (int kk = 0; kk < 64; kk++) {
            const int kl = wv * 64 + kk;                       // uniform
            float h = Hc[lane * 256 + (kl ^ (lane & 31))];
            const float* w2r = w2base + kl * Dm;               // uniform -> s_load
            #pragma unroll
            for (int d = 0; d < Dm; d++) acc[d] += h * w2r[d];
        }
    }

    __syncthreads();
    // cross-wave reduction through (reused) LDS
    float* red = Hc;
    #pragma unroll
    for (int d = 0; d < Dm; d++) red[(wv * 64 + lane) * Dm + d] = acc[d];
    __syncthreads();

    if (wv == 0) {
        #pragma unroll
        for (int w = 1; w < 4; w++)
            #pragma unroll
            for (int d = 0; d < Dm; d++)
                acc[d] += red[(w * 64 + lane) * Dm + d];

        const int row = row0 + lane;
        float y[Dm];
        #pragma unroll
        for (int d = 0; d < Dm; d++) {
            y[d] = xg[(size_t)row * Dm + d] + acc[d] + b2l[d];
            xg[(size_t)row * Dm + d] = y[d];
        }
        if (do_tail) {
            ln_qkv_write(row, y, layer + 1, Wq, bq, Wk, bk, Wv, bv,
                         ln1a, ln1b, qb, kb, vb);
        }
    }
}

// ---------------------------------------------------------------------------
// k_prep: tiny per-launch precompute of the collapsed tail:
//   M[half][s][n] = sum_j llW[s,j] * flW[half*128+j, n]         (2*43*7)
//   PS1[i*7+n]    = c1[n] + ll2b[i]*S1[n]                        (896)
//   QS2[j*7+n]    = c2[n] + ll2b[j]*S2[n] + flb[n]               (896)
// ---------------------------------------------------------------------------
__global__ __launch_bounds__(256) void k_prep(
    const float* __restrict__ llW, const float* __restrict__ llb,
    const float* __restrict__ flW, const float* __restrict__ flb,
    const float* __restrict__ ll2b,
    float* __restrict__ Mw, float* __restrict__ PS1, float* __restrict__ QS2)
{
    __shared__ float M[2][Sq][Nb];
    __shared__ float cc[2][Nb];
    __shared__ float SS[2][Nb];
    const int tid = threadIdx.x;

    for (int m = tid; m < 602; m += 256) {
        int half = m / 301, rem = m - half * 301;
        int s = rem / 7, n = rem - 7 * s;
        float a = 0.f;
        for (int jj = 0; jj < Am; jj++)
            a += llW[s * Am + jj] * flW[(half * Am + jj) * Nb + n];
        M[half][s][n] = a;
    }
    if (tid < 14) {
        int half = tid / 7, n = tid - 7 * (tid / 7);
        float a = 0.f;
        for (int jj = 0; jj < Am; jj++)
            a += llb[jj] * flW[(half * Am + jj) * Nb + n];
        cc[half][n] = a;
    }
    __syncthreads();
    if (tid < 14) {
        int half = tid / 7, n = tid - 7 * (tid / 7);
        float s2 = 0.f;
        for (int s = 0; s < Sq; s++) s2 += M[half][s][n];
        SS[half][n] = s2;
    }
    __syncthreads();
    const float* Mf = (const float*)M;
    for (int m = tid; m < 602; m += 256) Mw[m] = Mf[m];
    for (int m = tid; m < 896; m += 256) {
        int i = m / 7, n = m - 7 * i;
        PS1[m] = cc[0][n] + ll2b[i] * SS[0][n];
        QS2[m] = cc[1][n] + ll2b[i] * SS[1][n] + flb[n];
    }
}

// ---------------------------------------------------------------------------
// k_out: block = (i-chunk of 32, batch b). Computes T (18x7 per half) from
// x[b], then P-chunk (32x7) and QB (128x7 with fl_b folded), and streams the
// 32*896-float output tile with coalesced stores. Pure-BW bound.
// ---------------------------------------------------------------------------
__global__ __launch_bounds__(256) void k_out(
    const float* __restrict__ xg, const float* __restrict__ ll2W,
    const float* __restrict__ Mw, const float* __restrict__ PS1,
    const float* __restrict__ QS2, float* __restrict__ out)
{
    __shared__ float xb[Sq * Dm];       // 774
    __shared__ float M[602];
    __shared__ float T[2][Dm][Nb];
    __shared__ float Pc[32 * Nb];       // 224
    __shared__ float QBs[Am * Nb];      // 896

    const int b = blockIdx.y, chunk = blockIdx.x, tid = threadIdx.x;

    for (int e = tid; e < Sq * Dm; e += 256) xb[e] = xg[b * (Sq * Dm) + e];
    for (int m = tid; m < 602; m += 256) M[m] = Mw[m];
    __syncthreads();

    for (int m = tid; m < 252; m += 256) {
        int half = m / 126, rem = m - half * 126;
        int d = rem / 7, n = rem - 7 * d;
        float a = 0.f;
        for (int s = 0; s < Sq; s++)
            a += xb[s * Dm + d] * M[half * 301 + s * 7 + n];
        T[half][d][n] = a;
    }
    __syncthreads();

    for (int m = tid; m < 224; m += 256) {
        int il = m / 7, n = m - 7 * il;
        int i = chunk * 32 + il;
        float a = PS1[i * 7 + n];
        #pragma unroll
        for (int d = 0; d < Dm; d++) a += T[0][d][n] * ll2W[d * Am + i];
        Pc[m] = a;
    }
    for (int e = tid; e < 896; e += 256) {
        int jj = e / 7, n = e - 7 * jj;
        float a = QS2[e];
        #pragma unroll
        for (int d = 0; d < Dm; d++) a += T[1][d][n] * ll2W[d * Am + jj];
        QBs[e] = a;
    }
    __syncthreads();

    const size_t base = (size_t)b * (Am * Am * Nb) + (size_t)chunk * 32 * 896;
    for (int il = 0; il < 32; il++) {
        const size_t ob = base + (size_t)il * 896;
        for (int e = tid; e < 896; e += 256) {
            int n = e % 7;
            out[ob + e] = Pc[il * 7 + n] + QBs[e];
        }
    }
}

} // namespace

// ---------------------------------------------------------------------------
extern "C" void kernel_launch(void* const* d_in, const int* in_sizes, int n_in,
                              void* d_out, int out_size, void* d_ws, size_t ws_size,
                              hipStream_t stream)
{
    (void)in_sizes; (void)n_in; (void)out_size; (void)ws_size;

    const float* src  = (const float*)d_in[0];
    const int*   mask = (const int*)  d_in[1];
    // d_in[2] = max_atoms (always 128)
    const float* Wq   = (const float*)d_in[3];
    const float* bq   = (const float*)d_in[4];
    const float* Wk   = (const float*)d_in[5];
    const float* bk   = (const float*)d_in[6];
    const float* Wv   = (const float*)d_in[7];
    const float* bv   = (const float*)d_in[8];
    const float* Wo   = (const float*)d_in[9];
    const float* bo   = (const float*)d_in[10];
    const float* ln1a = (const float*)d_in[11];
    const float* ln1b = (const float*)d_in[12];
    const float* ln2a = (const float*)d_in[13];
    const float* ln2b = (const float*)d_in[14];
    const float* fW1  = (const float*)d_in[15];
    const float* fb1  = (const float*)d_in[16];
    const float* fW2  = (const float*)d_in[17];
    const float* fb2  = (const float*)d_in[18];
    const float* ll2W = (const float*)d_in[19];
    const float* ll2b = (const float*)d_in[20];
    const float* llW  = (const float*)d_in[21];
    const float* llb  = (const float*)d_in[22];
    const float* flW  = (const float*)d_in[23];
    const float* flb  = (const float*)d_in[24];
    float* out = (float*)d_out;

    float* ws  = (float*)d_ws;
    float* xg  = ws;                        // 198144
    float* x2g = ws + 1 * 198144;
    float* qb  = ws + 2 * 198144;
    float* kb  = ws + 3 * 198144;
    float* vb  = ws + 4 * 198144;
    float* Mw  = ws + 5 * 198144;           // 602 (pad to 604)
    float* PS1 = Mw + 604;                  // 896
    float* QS2 = PS1 + 896;                 // 896  -> total ~3.97 MB

    k_prep<<<1, 256, 0, stream>>>(llW, llb, flW, flb, ll2b, Mw, PS1, QS2);
    k_init<<<43, 256, 0, stream>>>(src, xg, Wq, bq, Wk, bk, Wv, bv,
                                   ln1a, ln1b, qb, kb, vb);
    for (int i = 0; i < 6; i++) {
        k_attn<<<256, 64, 0, stream>>>(i, qb, kb, vb, xg, x2g, mask,
                                       Wo, bo, ln2a, ln2b);
        k_ffn<<<172, 256, 0, stream>>>(i, x2g, xg, fW1, fb1, fW2, fb2,
                                       (i < 5) ? 1 : 0,
                                       Wq, bq, Wk, bk, Wv, bv,
                                       ln1a, ln1b, qb, kb, vb);
    }
    k_out<<<dim3(4, 256), 256, 0, stream>>>(xg, ll2W, Mw, PS1, QS2, out);
}

// Round 3
// 734.081 us; speedup vs baseline: 2.4121x; 2.4121x over previous
//
#include <hip/hip_runtime.h>
#include <math.h>

namespace {

constexpr int Sq = 43;
constexpr int Dm = 18;
constexpr int Dff = 2048;
constexpr int Am = 128;
constexpr int Nb = 7;
constexpr int NR = 11008;          // B*SEQ rows
constexpr int RSZ = NR * Dm;       // 198144 floats
constexpr float EPSf = 1e-6f;

// ---------------------------------------------------------------------------
// LN1 + QKV projection for one row (y[18] in registers), writes q/k/v rows.
// Weight reads are lane-uniform -> scalar loads.
// ---------------------------------------------------------------------------
__device__ __forceinline__ void ln_qkv_write(
    int row, const float* y, int ly,
    const float* __restrict__ Wq, const float* __restrict__ bq,
    const float* __restrict__ Wk, const float* __restrict__ bk,
    const float* __restrict__ Wv, const float* __restrict__ bv,
    const float* __restrict__ ln1a, const float* __restrict__ ln1b,
    float* __restrict__ qb, float* __restrict__ kb, float* __restrict__ vb)
{
    float mu = 0.f;
    #pragma unroll
    for (int d = 0; d < Dm; d++) mu += y[d];
    mu *= (1.f / Dm);
    float var = 0.f;
    #pragma unroll
    for (int d = 0; d < Dm; d++) { float t = y[d] - mu; var += t * t; }
    var *= (1.f / (Dm - 1));                 // ddof=1
    float isd = 1.f / (sqrtf(var) + EPSf);   // eps on sd
    float x2[Dm];
    #pragma unroll
    for (int d = 0; d < Dm; d++)
        x2[d] = ln1a[ly * Dm + d] * (y[d] - mu) * isd + ln1b[ly * Dm + d];
    const float* wq = Wq + ly * Dm * Dm;
    const float* wk = Wk + ly * Dm * Dm;
    const float* wv = Wv + ly * Dm * Dm;
    #pragma unroll 3
    for (int d = 0; d < Dm; d++) {
        float aq = bq[ly * Dm + d];
        float ak = bk[ly * Dm + d];
        float av = bv[ly * Dm + d];
        #pragma unroll
        for (int dd = 0; dd < Dm; dd++) {
            aq += x2[dd] * wq[dd * Dm + d];
            ak += x2[dd] * wk[dd * Dm + d];
            av += x2[dd] * wv[dd * Dm + d];
        }
        qb[(size_t)row * Dm + d] = aq;
        kb[(size_t)row * Dm + d] = ak;
        vb[(size_t)row * Dm + d] = av;
    }
}

// ---------------------------------------------------------------------------
// k_init: xA = src, LN1+QKV layer 0.
// ---------------------------------------------------------------------------
__global__ __launch_bounds__(256) void k_init(
    const float* __restrict__ src, float* __restrict__ xg,
    const float* __restrict__ Wq, const float* __restrict__ bq,
    const float* __restrict__ Wk, const float* __restrict__ bk,
    const float* __restrict__ Wv, const float* __restrict__ bv,
    const float* __restrict__ ln1a, const float* __restrict__ ln1b,
    float* __restrict__ qb, float* __restrict__ kb, float* __restrict__ vb)
{
    int row = blockIdx.x * 256 + threadIdx.x;   // 43 * 256 = 11008 exact
    float y[Dm];
    #pragma unroll
    for (int d = 0; d < Dm; d++) {
        y[d] = src[(size_t)row * Dm + d];
        xg[(size_t)row * Dm + d] = y[d];
    }
    ln_qkv_write(row, y, 0, Wq, bq, Wk, bk, Wv, bv, ln1a, ln1b, qb, kb, vb);
}

// ---------------------------------------------------------------------------
// k_wprep: W1T[l][j][d] = W1[l][d][j]  (contiguous rows for uniform s_load)
// ---------------------------------------------------------------------------
__global__ __launch_bounds__(256) void k_wprep(
    const float* __restrict__ W1g, float* __restrict__ W1T)
{
    int idx = blockIdx.x * 256 + threadIdx.x;
    if (idx >= 6 * Dff * Dm) return;
    int l = idx / (Dff * Dm);
    int r = idx - l * (Dff * Dm);
    int j = r / Dm;
    int d = r - j * Dm;
    W1T[idx] = W1g[(size_t)l * Dm * Dff + (size_t)d * Dff + j];
}

// ---------------------------------------------------------------------------
// k_attn: block = batch (256 blocks x 192 thr). wave = head, lane = query.
// K/V rows + mask are wave-uniform -> s_load. Then per-row tail (proj,
// residual, LN2, b2-folded seed of next-x) on threads 0..42.
// ---------------------------------------------------------------------------
__global__ __launch_bounds__(192) void k_attn(
    int layer,
    const float* __restrict__ qb, const float* __restrict__ kb,
    const float* __restrict__ vb,
    const float* __restrict__ xg,      // current x (residual base)
    float* __restrict__ xn,            // next-x seed = y + b2
    float* __restrict__ x2g,           // LN2(y)
    const int* __restrict__ maskg,
    const float* __restrict__ Wo, const float* __restrict__ bo,
    const float* __restrict__ ln2a, const float* __restrict__ ln2b,
    const float* __restrict__ b2g)
{
    __shared__ float o_s[Sq * Dm];
    const int b    = blockIdx.x;
    const int tid  = threadIdx.x;
    const int lane = tid & 63;
    const int h    = __builtin_amdgcn_readfirstlane(tid >> 6);  // 0..2
    const float scale = 0.40824829046386296f;  // 1/sqrt(6)

    if (lane < Sq) {
        const int i = lane;
        float qv[6];
        #pragma unroll
        for (int d = 0; d < 6; d++)
            qv[d] = qb[((size_t)b * Sq + i) * Dm + h * 6 + d];

        float mx = -1e30f;
        for (int j = 0; j < Sq; j++) {
            const float* kr = kb + ((size_t)b * Sq + j) * Dm + h * 6;  // uniform
            float t = 0.f;
            #pragma unroll
            for (int d = 0; d < 6; d++) t += qv[d] * kr[d];
            t *= scale;
            if (maskg[b * Sq + j] == 0) t = -1e9f;
            mx = fmaxf(mx, t);
        }
        float sum = 0.f;
        float o6[6];
        #pragma unroll
        for (int d = 0; d < 6; d++) o6[d] = 0.f;
        for (int j = 0; j < Sq; j++) {
            const float* kr = kb + ((size_t)b * Sq + j) * Dm + h * 6;  // uniform
            const float* vr = vb + ((size_t)b * Sq + j) * Dm + h * 6;  // uniform
            float t = 0.f;
            #pragma unroll
            for (int d = 0; d < 6; d++) t += qv[d] * kr[d];
            t *= scale;
            if (maskg[b * Sq + j] == 0) t = -1e9f;
            float e = __expf(t - mx);
            sum += e;
            #pragma unroll
            for (int d = 0; d < 6; d++) o6[d] += e * vr[d];
        }
        float inv = 1.f / sum;
        #pragma unroll
        for (int d = 0; d < 6; d++) o_s[i * Dm + h * 6 + d] = o6[d] * inv;
    }
    __syncthreads();

    if (tid < Sq) {
        const int row = b * Sq + tid;
        float o[Dm];
        #pragma unroll
        for (int d = 0; d < Dm; d++) o[d] = o_s[tid * Dm + d];
        const float* wo = Wo + layer * Dm * Dm;
        float y[Dm];
        #pragma unroll 3
        for (int d = 0; d < Dm; d++) {
            float t = bo[layer * Dm + d];
            #pragma unroll
            for (int dd = 0; dd < Dm; dd++) t += o[dd] * wo[dd * Dm + d];
            y[d] = xg[(size_t)row * Dm + d] + t;
        }
        // seed next-x with b2 folded in; FFN partials get summed in k_post
        #pragma unroll
        for (int d = 0; d < Dm; d++)
            xn[(size_t)row * Dm + d] = y[d] + b2g[layer * Dm + d];
        // LN2 -> x2g
        float mu = 0.f;
        #pragma unroll
        for (int d = 0; d < Dm; d++) mu += y[d];
        mu *= (1.f / Dm);
        float var = 0.f;
        #pragma unroll
        for (int d = 0; d < Dm; d++) { float t = y[d] - mu; var += t * t; }
        var *= (1.f / (Dm - 1));
        float isd = 1.f / (sqrtf(var) + EPSf);
        #pragma unroll
        for (int d = 0; d < Dm; d++)
            x2g[(size_t)row * Dm + d] =
                ln2a[layer * Dm + d] * (y[d] - mu) * isd + ln2b[layer * Dm + d];
    }
}

// ---------------------------------------------------------------------------
// k_ffn: 688 blocks = 172 row-groups x 4 hidden-chunks. 256 thr = 4 waves.
// wave w handles j in [q*512 + w*128, +128), lane = row (64 rows/group).
// W1T/W2 rows are contiguous + wave-uniform -> s_load feeding v_fmac(sgpr).
// In-block 4-wave LDS reduce -> partial buffer P[q].
// ---------------------------------------------------------------------------
__global__ __launch_bounds__(256) void k_ffn(
    int layer, const float* __restrict__ x2g,
    const float* __restrict__ W1T, const float* __restrict__ b1g,
    const float* __restrict__ W2g, float* __restrict__ P)
{
    __shared__ float Ls[4 * 64 * Dm];   // 18 KiB

    const int tid  = threadIdx.x;
    const int lane = tid & 63;
    const int wv   = __builtin_amdgcn_readfirstlane(tid >> 6);
    const int rg   = blockIdx.x >> 2;
    const int q    = blockIdx.x & 3;
    const int row  = rg * 64 + lane;
    const int j0   = q * 512 + wv * 128;

    const float* w1 = W1T + (size_t)layer * Dff * Dm;
    const float* w2 = W2g + (size_t)layer * Dff * Dm;
    const float* b1 = b1g + layer * Dff;

    float x[Dm];
    #pragma unroll
    for (int d = 0; d < Dm; d++) x[d] = x2g[(size_t)row * Dm + d];

    float acc[Dm];
    #pragma unroll
    for (int d = 0; d < Dm; d++) acc[d] = 0.f;

    #pragma unroll 2
    for (int jj = 0; jj < 128; jj++) {
        const int j = j0 + jj;                    // wave-uniform
        const float* r1 = w1 + (size_t)j * Dm;    // uniform -> s_load
        const float* r2 = w2 + (size_t)j * Dm;    // uniform -> s_load
        float hsum = b1[j];
        #pragma unroll
        for (int d = 0; d < Dm; d++) hsum += x[d] * r1[d];
        hsum = fmaxf(hsum, 0.f);
        #pragma unroll
        for (int d = 0; d < Dm; d++) acc[d] += hsum * r2[d];
    }

    #pragma unroll
    for (int d = 0; d < Dm; d++) Ls[wv * 1152 + lane * Dm + d] = acc[d];
    __syncthreads();
    for (int e = tid; e < 1152; e += 256) {
        float s = Ls[e] + Ls[1152 + e] + Ls[2304 + e] + Ls[3456 + e];
        P[(size_t)q * RSZ + (size_t)rg * 1152 + e] = s;
    }
}

// ---------------------------------------------------------------------------
// k_post: finalize x = seed + sum(partials); then LN1+QKV for next layer.
// ---------------------------------------------------------------------------
__global__ __launch_bounds__(256) void k_post(
    int layer, float* __restrict__ xn, const float* __restrict__ P,
    int do_tail,
    const float* __restrict__ Wq, const float* __restrict__ bq,
    const float* __restrict__ Wk, const float* __restrict__ bk,
    const float* __restrict__ Wv, const float* __restrict__ bv,
    const float* __restrict__ ln1a, const float* __restrict__ ln1b,
    float* __restrict__ qb, float* __restrict__ kb, float* __restrict__ vb)
{
    int row = blockIdx.x * 256 + threadIdx.x;
    float y[Dm];
    #pragma unroll
    for (int d = 0; d < Dm; d++) {
        size_t o = (size_t)row * Dm + d;
        float t = xn[o] + P[o] + P[RSZ + o] + P[2 * (size_t)RSZ + o]
                        + P[3 * (size_t)RSZ + o];
        y[d] = t;
        xn[o] = t;
    }
    if (do_tail)
        ln_qkv_write(row, y, layer + 1, Wq, bq, Wk, bk, Wv, bv,
                     ln1a, ln1b, qb, kb, vb);
}

// ---------------------------------------------------------------------------
// k_prep: collapsed-tail precompute (unchanged).
// ---------------------------------------------------------------------------
__global__ __launch_bounds__(256) void k_prep(
    const float* __restrict__ llW, const float* __restrict__ llb,
    const float* __restrict__ flW, const float* __restrict__ flb,
    const float* __restrict__ ll2b,
    float* __restrict__ Mw, float* __restrict__ PS1, float* __restrict__ QS2)
{
    __shared__ float M[2][Sq][Nb];
    __shared__ float cc[2][Nb];
    __shared__ float SS[2][Nb];
    const int tid = threadIdx.x;

    for (int m = tid; m < 602; m += 256) {
        int half = m / 301, rem = m - half * 301;
        int s = rem / 7, n = rem - 7 * s;
        float a = 0.f;
        for (int jj = 0; jj < Am; jj++)
            a += llW[s * Am + jj] * flW[(half * Am + jj) * Nb + n];
        M[half][s][n] = a;
    }
    if (tid < 14) {
        int half = tid / 7, n = tid - 7 * (tid / 7);
        float a = 0.f;
        for (int jj = 0; jj < Am; jj++)
            a += llb[jj] * flW[(half * Am + jj) * Nb + n];
        cc[half][n] = a;
    }
    __syncthreads();
    if (tid < 14) {
        int half = tid / 7, n = tid - 7 * (tid / 7);
        float s2 = 0.f;
        for (int s = 0; s < Sq; s++) s2 += M[half][s][n];
        SS[half][n] = s2;
    }
    __syncthreads();
    const float* Mf = (const float*)M;
    for (int m = tid; m < 602; m += 256) Mw[m] = Mf[m];
    for (int m = tid; m < 896; m += 256) {
        int i = m / 7, n = m - 7 * i;
        PS1[m] = cc[0][n] + ll2b[i] * SS[0][n];
        QS2[m] = cc[1][n] + ll2b[i] * SS[1][n] + flb[n];
    }
}

// ---------------------------------------------------------------------------
// k_out: (i-chunk, batch) blocks; streams 117 MB output. BW-bound.
// ---------------------------------------------------------------------------
__global__ __launch_bounds__(256) void k_out(
    const float* __restrict__ xg, const float* __restrict__ ll2W,
    const float* __restrict__ Mw, const float* __restrict__ PS1,
    const float* __restrict__ QS2, float* __restrict__ out)
{
    __shared__ float xb[Sq * Dm];
    __shared__ float M[602];
    __shared__ float T[2][Dm][Nb];
    __shared__ float Pc[32 * Nb];
    __shared__ float QBs[Am * Nb];

    const int b = blockIdx.y, chunk = blockIdx.x, tid = threadIdx.x;

    for (int e = tid; e < Sq * Dm; e += 256) xb[e] = xg[(size_t)b * (Sq * Dm) + e];
    for (int m = tid; m < 602; m += 256) M[m] = Mw[m];
    __syncthreads();

    for (int m = tid; m < 252; m += 256) {
        int half = m / 126, rem = m - half * 126;
        int d = rem / 7, n = rem - 7 * d;
        float a = 0.f;
        for (int s = 0; s < Sq; s++)
            a += xb[s * Dm + d] * M[half * 301 + s * 7 + n];
        T[half][d][n] = a;
    }
    __syncthreads();

    for (int m = tid; m < 224; m += 256) {
        int il = m / 7, n = m - 7 * il;
        int i = chunk * 32 + il;
        float a = PS1[i * 7 + n];
        #pragma unroll
        for (int d = 0; d < Dm; d++) a += T[0][d][n] * ll2W[d * Am + i];
        Pc[m] = a;
    }
    for (int e = tid; e < 896; e += 256) {
        int jj = e / 7, n = e - 7 * jj;
        float a = QS2[e];
        #pragma unroll
        for (int d = 0; d < Dm; d++) a += T[1][d][n] * ll2W[d * Am + jj];
        QBs[e] = a;
    }
    __syncthreads();

    // per-thread fixed element set: precompute n and QB once
    float qv[4]; int nn[4]; int ee[4]; int cnt = 0;
    for (int e = tid; e < 896; e += 256) {
        ee[cnt] = e; nn[cnt] = e % 7; qv[cnt] = QBs[e]; cnt++;
    }
    const size_t base = (size_t)b * (Am * Am * Nb) + (size_t)chunk * 32 * 896;
    for (int il = 0; il < 32; il++) {
        const size_t ob = base + (size_t)il * 896;
        for (int c = 0; c < cnt; c++)
            out[ob + ee[c]] = Pc[il * 7 + nn[c]] + qv[c];
    }
}

} // namespace

// ---------------------------------------------------------------------------
extern "C" void kernel_launch(void* const* d_in, const int* in_sizes, int n_in,
                              void* d_out, int out_size, void* d_ws, size_t ws_size,
                              hipStream_t stream)
{
    (void)in_sizes; (void)n_in; (void)out_size; (void)ws_size;

    const float* src  = (const float*)d_in[0];
    const int*   mask = (const int*)  d_in[1];
    const float* Wq   = (const float*)d_in[3];
    const float* bq   = (const float*)d_in[4];
    const float* Wk   = (const float*)d_in[5];
    const float* bk   = (const float*)d_in[6];
    const float* Wv   = (const float*)d_in[7];
    const float* bv   = (const float*)d_in[8];
    const float* Wo   = (const float*)d_in[9];
    const float* bo   = (const float*)d_in[10];
    const float* ln1a = (const float*)d_in[11];
    const float* ln1b = (const float*)d_in[12];
    const float* ln2a = (const float*)d_in[13];
    const float* ln2b = (const float*)d_in[14];
    const float* fW1  = (const float*)d_in[15];
    const float* fb1  = (const float*)d_in[16];
    const float* fW2  = (const float*)d_in[17];
    const float* fb2  = (const float*)d_in[18];
    const float* ll2W = (const float*)d_in[19];
    const float* ll2b = (const float*)d_in[20];
    const float* llW  = (const float*)d_in[21];
    const float* llb  = (const float*)d_in[22];
    const float* flW  = (const float*)d_in[23];
    const float* flb  = (const float*)d_in[24];
    float* out = (float*)d_out;

    float* ws  = (float*)d_ws;
    float* xA  = ws;                         // 198144
    float* xB  = ws + 1 * (size_t)RSZ;
    float* x2g = ws + 2 * (size_t)RSZ;
    float* qb  = ws + 3 * (size_t)RSZ;
    float* kb  = ws + 4 * (size_t)RSZ;
    float* vb  = ws + 5 * (size_t)RSZ;
    float* P   = ws + 6 * (size_t)RSZ;       // 4 * 198144
    float* W1T = ws + 10 * (size_t)RSZ;      // 221184
    float* Mw  = W1T + 221184;               // 602 (pad 604)
    float* PS1 = Mw + 604;                   // 896
    float* QS2 = PS1 + 896;                  // 896   total ~8.8 MB

    k_prep<<<1, 256, 0, stream>>>(llW, llb, flW, flb, ll2b, Mw, PS1, QS2);
    k_wprep<<<(6 * Dff * Dm + 255) / 256, 256, 0, stream>>>(fW1, W1T);
    k_init<<<43, 256, 0, stream>>>(src, xA, Wq, bq, Wk, bk, Wv, bv,
                                   ln1a, ln1b, qb, kb, vb);
    for (int i = 0; i < 6; i++) {
        const float* Xi = (i % 2 == 0) ? xA : xB;
        float*       Xn = (i % 2 == 0) ? xB : xA;
        k_attn<<<256, 192, 0, stream>>>(i, qb, kb, vb, Xi, Xn, x2g, mask,
                                        Wo, bo, ln2a, ln2b, fb2);
        k_ffn<<<688, 256, 0, stream>>>(i, x2g, W1T, fb1, fW2, P);
        k_post<<<43, 256, 0, stream>>>(i, Xn, P, (i < 5) ? 1 : 0,
                                       Wq, bq, Wk, bk, Wv, bv,
                                       ln1a, ln1b, qb, kb, vb);
    }
    k_out<<<dim3(4, 256), 256, 0, stream>>>(xA, ll2W, Mw, PS1, QS2, out);
}